// Round 13
// baseline (131.078 us; speedup 1.0000x reference)
//
#include <hip/hip_runtime.h>

// CatNet_76553497084407 — SLAYER-style spiking CNN, fully collapsed over time.
//
// Only spike COUNTS flow between layers, so T=50 is never materialized.
// R13: the monolithic per-sample phase chain is latency-bound and three
// structural attacks on its stalls failed (R8b/R11/R12). Split into 4
// barrier-free kernels with intermediates in d_ws (8.6 MB): conv kernels run
// as 2048 independent 128-thread blocks (zero LDS, zero __syncthreads,
// 8 blocks/CU) so wave-level scheduling hides all latency.
// Kept: guarded closed-form IF rate (R3), r1 even/odd split so conv2+pool
// windows are stride-1 (R8a) — now as global layout; wave-uniform weight
// bases via blockIdx.y (scalar loads). Per-neuron drives bit-identical to
// the R9 kernel (same tap values and FMA order).
// Fallback: if ws_size < needed, dispatch the proven R9 monolithic kernel.

#define T_STEPS 50
#define THETA   0.9999f

__device__ __forceinline__ float spike_rate(float a) {
    constexpr float INV = 50.0f / 0.9999f;
    float t = a * INV;
    float c = fminf(fmaxf(floorf(t), 0.0f), 50.0f);
    // fall back to the exact 50-step f32 sim when t is near an integer
    bool risky = (t > 0.5f) && (fabsf(t - rintf(t)) < 5e-4f);
    if (__ballot(risky)) {
        float v = 0.f, cnt = 0.f;
#pragma unroll 1
        for (int k = 0; k < T_STEPS; ++k) {
            v += a;
            float s = (v >= THETA) ? 1.0f : 0.0f;
            v -= s * THETA;
            cnt += s;
        }
        c = cnt;
    }
    return c / 50.0f;   // true divide: match reference sum/T rounding
}

// sizes (floats)
#define R1_PER_N   (16 * 91)            // even/odd each
#define R1_TOTAL   (256 * R1_PER_N)     // 372736
#define R3_PER_N   (32 * 89)
#define R3_TOTAL   (256 * R3_PER_N)     // 729088
#define R4_PER_N   (32 * 83)
#define R4_TOTAL   (256 * R4_PER_N)     // 679936

// ---- K1: time-sum + conv1 (1->16, k=3, pad=1) + rate -> r1e/r1o ----
extern "C" __global__ void __launch_bounds__(512)
k1_conv1(const float* __restrict__ x, const float* __restrict__ w1,
         const float* __restrict__ b1,
         float* __restrict__ r1e, float* __restrict__ r1o)
{
    const int n = blockIdx.x;
    const int tid = threadIdx.x;
    __shared__ float xbar[182];
    if (tid == 448) { xbar[0] = 0.f; xbar[181] = 0.f; }
    // zero pads: r1e[.][0] (pidx 0), r1o[.][90] (pidx 181)
    if (tid >= 464 && tid < 480) r1e[(n * 16 + (tid - 464)) * 91 + 0]  = 0.f;
    if (tid >= 480 && tid < 496) r1o[(n * 16 + (tid - 480)) * 91 + 90] = 0.f;

    const float* xn = x + (size_t)n * (180 * 50);
    if (tid < 360) {
        const int h = tid >> 1, q = tid & 1;
        const float2* row = (const float2*)(xn + h * 50);
        float sv = 0.f;
        for (int k = q; k < 25; k += 2) { float2 v = row[k]; sv += v.x + v.y; }
        sv += __shfl_xor(sv, 1, 2);
        if (q == 0) xbar[h + 1] = sv;
    }
    __syncthreads();

    for (int idx = tid; idx < 16 * 180; idx += 512) {
        int c = idx / 180, h = idx - c * 180;
        float a = w1[c*3+0] * xbar[h] + w1[c*3+1] * xbar[h+1] + w1[c*3+2] * xbar[h+2];
        a = a / 50.0f + b1[c];
        float r = spike_rate(a);
        int pidx = h + 1;
        if (pidx & 1) r1o[(n * 16 + c) * 91 + (pidx >> 1)] = r;
        else          r1e[(n * 16 + c) * 91 + (pidx >> 1)] = r;
    }
}

// ---- K2: conv2 (16->32, k=9, pad=1) + rate + pool(2)*1.1 + rate -> r3 ----
// grid (n=256, g=8); block 128 threads -> pool output p; 4 out-ch/thread.
extern "C" __global__ void __launch_bounds__(128)
k2_conv2pool(const float* __restrict__ r1e, const float* __restrict__ r1o,
             const float* __restrict__ w2, const float* __restrict__ b2,
             float* __restrict__ r3)
{
    const int n = blockIdx.x;
    const int g = blockIdx.y;                 // 0..7 (SGPR -> scalar weights)
    const int p0 = threadIdx.x;               // 0..127
    const bool act = p0 < 87;
    const int p = act ? p0 : 0;
    const float* wb = w2 + g * 4 * 144;       // [j][ci][kh], j stride 144
    const float* r1eb = r1e + n * R1_PER_N;
    const float* r1ob = r1o + n * R1_PER_N;

    float a0[4], a1[4];
#pragma unroll
    for (int j = 0; j < 4; ++j) { a0[j] = b2[g*4 + j]; a1[j] = a0[j]; }

#pragma unroll 2
    for (int ci = 0; ci < 16; ++ci) {
        float we[5], wo[5];
#pragma unroll
        for (int d = 0; d < 5; ++d) {
            we[d] = r1eb[ci * 91 + p + d];    // stride-1 across lanes
            wo[d] = r1ob[ci * 91 + p + d];
        }
#pragma unroll
        for (int j = 0; j < 4; ++j) {
            const float* wj = wb + j * 144 + ci * 9;
            // conv at h=2p (taps pidx 2p+kh) and h=2p+1, kh order preserved
            a0[j] += wj[0]*we[0] + wj[1]*wo[0] + wj[2]*we[1] + wj[3]*wo[1]
                   + wj[4]*we[2] + wj[5]*wo[2] + wj[6]*we[3] + wj[7]*wo[3]
                   + wj[8]*we[4];
            a1[j] += wj[0]*wo[0] + wj[1]*we[1] + wj[2]*wo[1] + wj[3]*we[2]
                   + wj[4]*wo[2] + wj[5]*we[3] + wj[6]*wo[3] + wj[7]*we[4]
                   + wj[8]*wo[4];
        }
    }
#pragma unroll
    for (int j = 0; j < 4; ++j) {
        float r20 = spike_rate(a0[j]);
        float r21 = spike_rate(a1[j]);
        float r3v = spike_rate(1.1f * (r20 + r21));
        if (act) {
            float* dst = r3 + (size_t)(n * 32 + g * 4 + j) * 89;
            dst[p + 1] = r3v;
            if (p0 == 0) { dst[0] = 0.f; dst[88] = 0.f; }   // conv3 pads
        }
    }
}

// ---- K3: conv3 (32->32, k=7, pad=1) + rate -> r4 ----
// grid (n=256, g=8); block 128 threads -> h; 4 out-ch/thread.
extern "C" __global__ void __launch_bounds__(128)
k3_conv3(const float* __restrict__ r3, const float* __restrict__ w3,
         const float* __restrict__ b3, float* __restrict__ r4)
{
    const int n = blockIdx.x;
    const int g4 = blockIdx.y * 4;            // SGPR -> scalar weights
    const int h0 = threadIdx.x;               // 0..127
    const bool act = h0 < 83;
    const int h = act ? h0 : 0;
    const float* wb = w3 + g4 * 224;          // [j][ci][kh], j stride 224
    const float* r3b = r3 + (size_t)n * R3_PER_N;

    float a[4];
#pragma unroll
    for (int j = 0; j < 4; ++j) a[j] = b3[g4 + j];

#pragma unroll 2
    for (int ci = 0; ci < 32; ++ci) {
        float rv[7];
#pragma unroll
        for (int kh = 0; kh < 7; ++kh) rv[kh] = r3b[ci * 89 + h + kh];
#pragma unroll
        for (int j = 0; j < 4; ++j) {
            const float* wj = wb + j * 224 + ci * 7;
#pragma unroll
            for (int kh = 0; kh < 7; ++kh)
                a[j] += wj[kh] * rv[kh];
        }
    }
#pragma unroll
    for (int j = 0; j < 4; ++j) {
        float r = spike_rate(a[j]);
        if (act) r4[(size_t)(n * 32 + g4 + j) * 83 + h] = r;
    }
}

// ---- K4: dense [32*83] -> 4 outputs; 1 wave per output ----
extern "C" __global__ void __launch_bounds__(256)
k4_dense(const float* __restrict__ r4, const float* __restrict__ wf,
         const float* __restrict__ bf, float* __restrict__ out)
{
    const int n = blockIdx.x;
    const int o = threadIdx.x >> 6;
    const int lane = threadIdx.x & 63;
    const float* r4n = r4 + (size_t)n * R4_PER_N;
    const float* wo  = wf + o * R4_PER_N;
    float acc = 0.f;
    for (int j = lane; j < R4_PER_N; j += 64)
        acc += r4n[j] * wo[j];
#pragma unroll
    for (int off = 32; off > 0; off >>= 1)
        acc += __shfl_down(acc, off, 64);
    if (lane == 0) out[n * 4 + o] = acc + bf[o];
}

// ---- Fallback: R9 monolithic kernel (proven: 41.5us, absmax 0.0) ----
extern "C" __global__ void __launch_bounds__(1024)
catnet_kernel(const float* __restrict__ x,
              const float* __restrict__ w1, const float* __restrict__ b1,
              const float* __restrict__ w2, const float* __restrict__ b2,
              const float* __restrict__ w3, const float* __restrict__ b3,
              const float* __restrict__ wf, const float* __restrict__ bf,
              float* __restrict__ out)
{
    const int n    = blockIdx.x;
    const int tid  = threadIdx.x;
    const int wave = tid >> 6;
    const int lane = tid & 63;

    __shared__ float xbar[182];
    __shared__ float r1e[16][91];
    __shared__ float r1o[16][91];
    __shared__ float r3p[32][89];
    __shared__ float r4s[32][83];
    __shared__ float part[16];

    if (tid < 16)              { r1e[tid][0] = 0.f; r1o[tid][90] = 0.f; }
    if (tid >= 32 && tid < 64) { r3p[tid-32][0] = 0.f; r3p[tid-32][88] = 0.f; }
    if (tid == 64)             { xbar[0] = 0.f; xbar[181] = 0.f; }

    const float* xn = x + (size_t)n * (180 * 50);
    if (tid < 720) {
        const int h = tid >> 2, q = tid & 3;
        const float2* row = (const float2*)(xn + h * 50);
        float s = 0.f;
        for (int k = q; k < 25; k += 4) { float2 v = row[k]; s += v.x + v.y; }
        s += __shfl_xor(s, 1, 4);
        s += __shfl_xor(s, 2, 4);
        if (q == 0) xbar[h + 1] = s;
    }
    __syncthreads();

    for (int idx = tid; idx < 16 * 180; idx += 1024) {
        int c = idx / 180, h = idx - c * 180;
        float a = w1[c*3+0] * xbar[h] + w1[c*3+1] * xbar[h+1] + w1[c*3+2] * xbar[h+2];
        a = a / 50.0f + b1[c];
        float r = spike_rate(a);
        int pidx = h + 1;
        float* dst = (pidx & 1) ? &r1o[c][pidx >> 1] : &r1e[c][pidx >> 1];
        *dst = r;
    }
    __syncthreads();

    {
        const int g   = __builtin_amdgcn_readfirstlane(tid >> 7);
        const int p   = tid & 127;
        const bool act = p < 87;
        const int pr  = act ? p : 0;
        const float* wb = w2 + g * 4 * 144;

        float a0[4], a1[4];
#pragma unroll
        for (int j = 0; j < 4; ++j) { a0[j] = b2[g*4 + j]; a1[j] = a0[j]; }

#pragma unroll 2
        for (int ci = 0; ci < 16; ++ci) {
            float we[5], wo[5];
#pragma unroll
            for (int d = 0; d < 5; ++d) { we[d] = r1e[ci][pr + d]; wo[d] = r1o[ci][pr + d]; }
#pragma unroll
            for (int j = 0; j < 4; ++j) {
                const float* wj = wb + j * 144 + ci * 9;
                a0[j] += wj[0]*we[0] + wj[1]*wo[0] + wj[2]*we[1] + wj[3]*wo[1]
                       + wj[4]*we[2] + wj[5]*wo[2] + wj[6]*we[3] + wj[7]*wo[3]
                       + wj[8]*we[4];
                a1[j] += wj[0]*wo[0] + wj[1]*we[1] + wj[2]*wo[1] + wj[3]*we[2]
                       + wj[4]*wo[2] + wj[5]*we[3] + wj[6]*wo[3] + wj[7]*we[4]
                       + wj[8]*wo[4];
            }
        }
#pragma unroll
        for (int j = 0; j < 4; ++j) {
            float r20 = spike_rate(a0[j]);
            float r21 = spike_rate(a1[j]);
            float r3  = spike_rate(1.1f * (r20 + r21));
            if (act) r3p[g*4 + j][p + 1] = r3;
        }
    }
    __syncthreads();

    {
        const int g4   = __builtin_amdgcn_readfirstlane((wave >> 1) * 4);
        const int half = wave & 1;
        const int cnt  = half ? 41 : 42;
        const bool act = lane < cnt;
        const int h0   = half * 42 + (act ? lane : 0);
        const float* wb = w3 + g4 * 224;

        float a[4];
#pragma unroll
        for (int j = 0; j < 4; ++j) a[j] = b3[g4 + j];

#pragma unroll 2
        for (int ci = 0; ci < 32; ++ci) {
            float rv[7];
#pragma unroll
            for (int kh = 0; kh < 7; ++kh) rv[kh] = r3p[ci][h0 + kh];
#pragma unroll
            for (int j = 0; j < 4; ++j) {
                const float* wj = wb + j * 224 + ci * 7;
#pragma unroll
                for (int kh = 0; kh < 7; ++kh) a[j] += wj[kh] * rv[kh];
            }
        }
#pragma unroll
        for (int j = 0; j < 4; ++j) {
            float r = spike_rate(a[j]);
            if (act) r4s[g4 + j][h0] = r;
        }
    }
    __syncthreads();

    {
        const int o = wave >> 2, q = wave & 3;
        const float* r4f = &r4s[0][0];
        const float* wo  = wf + o * (32 * 83);
        float acc = 0.f;
        for (int j = q * 64 + lane; j < 32 * 83; j += 256)
            acc += r4f[j] * wo[j];
#pragma unroll
        for (int off = 32; off > 0; off >>= 1)
            acc += __shfl_down(acc, off, 64);
        if (lane == 0) part[wave] = acc;
    }
    __syncthreads();
    if (tid < 4) {
        float s = part[tid*4] + part[tid*4+1] + part[tid*4+2] + part[tid*4+3];
        out[n * 4 + tid] = s + bf[tid];
    }
}

extern "C" void kernel_launch(void* const* d_in, const int* in_sizes, int n_in,
                              void* d_out, int out_size, void* d_ws, size_t ws_size,
                              hipStream_t stream) {
    const float* x  = (const float*)d_in[0];
    const float* w1 = (const float*)d_in[1];
    const float* b1 = (const float*)d_in[2];
    const float* w2 = (const float*)d_in[3];
    const float* b2 = (const float*)d_in[4];
    const float* w3 = (const float*)d_in[5];
    const float* b3 = (const float*)d_in[6];
    const float* wf = (const float*)d_in[7];
    const float* bf = (const float*)d_in[8];
    float* outp = (float*)d_out;

    const size_t need = (size_t)(2 * R1_TOTAL + R3_TOTAL + R4_TOTAL) * sizeof(float);
    if (ws_size >= need) {
        float* r1e = (float*)d_ws;
        float* r1o = r1e + R1_TOTAL;
        float* r3  = r1o + R1_TOTAL;
        float* r4  = r3  + R3_TOTAL;
        k1_conv1   <<<dim3(256),    dim3(512), 0, stream>>>(x, w1, b1, r1e, r1o);
        k2_conv2pool<<<dim3(256, 8), dim3(128), 0, stream>>>(r1e, r1o, w2, b2, r3);
        k3_conv3   <<<dim3(256, 8), dim3(128), 0, stream>>>(r3, w3, b3, r4);
        k4_dense   <<<dim3(256),    dim3(256), 0, stream>>>(r4, wf, bf, outp);
    } else {
        // ws too small for intermediates: proven monolithic path
        catnet_kernel<<<dim3(256), dim3(1024), 0, stream>>>(
            x, w1, b1, w2, b2, w3, b3, wf, bf, outp);
    }
}